// Round 5
// baseline (22602.681 us; speedup 1.0000x reference)
//
#include <hip/hip_runtime.h>
#include <math.h>

// ---------------------------------------------------------------------------
// NCPDecoder: 3-cell CfC RNN, B=1024, T=256.
// Round 7->8: latency removal inside the unchanged R7 decomposition.
// R7 (8.42 ms bench / 9.75 ms prof): VALUBusy 58%, phase 37.5 us vs ~16 us
// max-pipe floor -> ~40% stall. Evidence: (1) fma4 issued its 4 broadcast
// ds_read_b128 then waited lgkmcnt right before the FMA burst; (2) VGPR=84
// cannot hold the 16-quad weight ping-pong + acc -> compiler sank weight
// prefetches to use points (vmcnt stall each block).
// R8: (a) activation k4-pair double-buffer: next pair's 8 ds_reads issue
// before current pair's 256 cyc of FMAs; (b) weight regs PERSIST across
// phases; mv4 reloads k4 0..3 at its END so the loads land during
// combine+barrier (cannot sink across __syncthreads); (c) launch_bounds
// (768,3) pins regalloc at 3 waves/SIMD; (d) combine spread over 640
// threads (row-jobs) to shorten the serial combine section.
// Per-accumulator FMA order unchanged -> identical numerics.
// ---------------------------------------------------------------------------

namespace {
constexpr int kBatch = 1024;
constexpr int kT     = 256;
constexpr int kDIN   = 128;
constexpr int kUNITS = 512;
constexpr int kINTER = 269;
constexpr int kCMD   = 179;
constexpr int kMOTOR = 64;
constexpr int kOUT   = 64;

constexpr int kCAT0 = kDIN + kINTER;    // 397
constexpr int kCAT1 = kINTER + kCMD;    // 448
constexpr int kCAT2 = kCMD + kMOTOR;    // 243

// real combined col counts (ff1 | ff2 | ta+tb)
constexpr int kC0r = 3 * kINTER;  // 807
constexpr int kC1r = 3 * kCMD;    // 537
constexpr int kC2r = 3 * kMOTOR;  // 192
// padded col counts, divisible by 4 (thread owns 4 strided cols)
constexpr int kC0p = 808;
constexpr int kC1p = 540;
constexpr int kC2p = 192;
// threads per cell (= colp/4)
constexpr int kP0 = 202;
constexpr int kP1 = 135;
constexpr int kP2 = 48;
// k4 depths padded to multiples of 4 ; LDS a-strides
constexpr int kK40 = 100;               // 397 -> 400
constexpr int kK41 = 112;               // 448 exact
constexpr int kK42 = 64;                // 243 -> 256
constexpr int kS0 = kK40 * 4;           // 400
constexpr int kS1 = kK41 * 4;           // 448
constexpr int kS2 = kK42 * 4;           // 256

constexpr int kQ0 = kK40 * kC0p;        // 80800 float4 quads
constexpr int kQ1 = kK41 * kC1p;        // 60480
constexpr int kQ2 = kK42 * kC2p;        // 12288
constexpr int kQ  = kQ0 + kQ1 + kQ2;    // 153568
constexpr int kBCN = kC0p + kC1p + kC2p;  // 1540 fused biases (padded coords)
constexpr int kBCOff = kQ * 4;          // float offset of biases in ws

constexpr int kMT = 4;     // batch rows per WG
constexpr int kNT = 768;   // threads per WG (12 waves)

// combine job ranges (row-level jobs, 4 rows per column)
constexpr int kJ0 = kINTER * kMT;            // 1076
constexpr int kJ1 = kJ0 + kCMD * kMT;        // 1792
constexpr int kJ2 = kJ1 + kMOTOR * kMT;      // 2048
constexpr int kCW = 640;                     // combine worker threads

static_assert(kK40 % 4 == 0 && kK41 % 4 == 0 && kK42 % 4 == 0, "pipeline");
static_assert(kC0p % 4 == 0 && kC1p % 4 == 0 && kC2p % 4 == 0, "4-col");
}  // namespace

// Mask element-width detection. mask0 row 0, columns 128..396 are the
// structurally all-true h-block (full = concat([m, ones(n_h,n_h)]) then .T).
__device__ __forceinline__ int detect_mask_mode(const void* m0) {
  const unsigned int* w = (const unsigned int*)m0;
  if (w[32] == 0x01010101u && w[33] == 0x01010101u &&
      w[34] == 0x01010101u && w[35] == 0x01010101u)
    return 0;  // uint8
  if (w[128] == 0x3F800000u && w[129] == 0x3F800000u && w[130] == 0x3F800000u)
    return 2;  // f32
  return 1;    // int32
}

__device__ __forceinline__ bool mask_at(const void* mk, int idx, int mode) {
  if (mode == 0) return ((const unsigned char*)mk)[idx] != 0;
  if (mode == 1) return ((const int*)mk)[idx] != 0;
  return ((const float*)mk)[idx] != 0.0f;
}

// ---------------------------------------------------------------------------
// Prep: packed masked/fused weights, layout W[cell][k4][col_padded][4].
// Pad cols/k-rows are exact zeros (so they contribute 0 to accumulators).
// ---------------------------------------------------------------------------
__global__ void prep_kernel(
    const void* __restrict__ m0_, const void* __restrict__ m1_,
    const void* __restrict__ m2_,
    const float* __restrict__ f1w0, const float* __restrict__ f2w0,
    const float* __restrict__ taw0, const float* __restrict__ tbw0,
    const float* __restrict__ f1w1, const float* __restrict__ f2w1,
    const float* __restrict__ taw1, const float* __restrict__ tbw1,
    const float* __restrict__ f1w2, const float* __restrict__ f2w2,
    const float* __restrict__ taw2, const float* __restrict__ tbw2,
    const float* __restrict__ f1b0, const float* __restrict__ f2b0,
    const float* __restrict__ tab0, const float* __restrict__ tbb0,
    const float* __restrict__ f1b1, const float* __restrict__ f2b1,
    const float* __restrict__ tab1, const float* __restrict__ tbb1,
    const float* __restrict__ f1b2, const float* __restrict__ f2b2,
    const float* __restrict__ tab2, const float* __restrict__ tbb2,
    float* __restrict__ ws) {
  int i = blockIdx.x * 256 + threadIdx.x;
  const int mode = detect_mask_mode(m0_);
  if (i < kQ) {
    int qi, NCp, ncols, cat, nh, baseq;
    const void* mk;
    const float *wf1, *wf2, *wta, *wtb;
    if (i < kQ0) {
      qi = i; NCp = kC0p; ncols = kC0r; cat = kCAT0; nh = kINTER; mk = m0_;
      wf1 = f1w0; wf2 = f2w0; wta = taw0; wtb = tbw0; baseq = 0;
    } else if (i < kQ0 + kQ1) {
      qi = i - kQ0; NCp = kC1p; ncols = kC1r; cat = kCAT1; nh = kCMD; mk = m1_;
      wf1 = f1w1; wf2 = f2w1; wta = taw1; wtb = tbw1; baseq = kQ0;
    } else {
      qi = i - kQ0 - kQ1; NCp = kC2p; ncols = kC2r; cat = kCAT2; nh = kMOTOR;
      mk = m2_;
      wf1 = f1w2; wf2 = f2w2; wta = taw2; wtb = tbw2; baseq = kQ0 + kQ1;
    }
    int k4 = qi / NCp;
    int j  = qi % NCp;
    float v[4] = {0.0f, 0.0f, 0.0f, 0.0f};
    if (j < ncols) {
#pragma unroll
      for (int kk = 0; kk < 4; ++kk) {
        int k = k4 * 4 + kk;
        float r = 0.0f;
        if (k < cat) {
          if (j < nh) {
            r = mask_at(mk, j * cat + k, mode) ? wf1[j * cat + k] : 0.0f;
          } else if (j < 2 * nh) {
            int jj = j - nh;
            r = mask_at(mk, jj * cat + k, mode) ? wf2[jj * cat + k] : 0.0f;
          } else {
            int jj = j - 2 * nh;
            r = wta[jj * cat + k] + wtb[jj * cat + k];
          }
        }
        v[kk] = r;
      }
    }
    ((float4*)ws)[baseq + qi] = make_float4(v[0], v[1], v[2], v[3]);
  } else if (i < kQ + kBCN) {
    int pos = i - kQ;
    int j = pos;
    int nh, ncols;
    const float *bf1, *bf2, *bta, *btb;
    if (j < kC0p) {
      nh = kINTER; ncols = kC0r;
      bf1 = f1b0; bf2 = f2b0; bta = tab0; btb = tbb0;
    } else if (j < kC0p + kC1p) {
      j -= kC0p; nh = kCMD; ncols = kC1r;
      bf1 = f1b1; bf2 = f2b1; bta = tab1; btb = tbb1;
    } else {
      j -= kC0p + kC1p; nh = kMOTOR; ncols = kC2r;
      bf1 = f1b2; bf2 = f2b2; bta = tab2; btb = tbb2;
    }
    float r = 0.0f;
    if (j < ncols) {
      if (j < nh) r = bf1[j];
      else if (j < 2 * nh) r = bf2[j - nh];
      else r = bta[j - 2 * nh] + btb[j - 2 * nh];
    }
    ws[kBCOff + pos] = r;
  }
}

// ---------------------------------------------------------------------------
// load one k4-row of 4 strided weight quads (cols j, j+P, j+2P, j+3P)
// ---------------------------------------------------------------------------
template <int NCOLS>
__device__ __forceinline__ void wload4(const float4* __restrict__ pw,
                                       float4 (&W)[4], int k4) {
  constexpr int P = NCOLS / 4;
#pragma unroll
  for (int c = 0; c < 4; ++c) W[c] = pw[k4 * NCOLS + c * P];
}

// 16 FMAs per pre-loaded activation quad (one k4, one row) x 4 cols.
__device__ __forceinline__ void fma4r(const float4 (&w)[4],
                                      const float4 (&av)[kMT],
                                      float (&acc)[4][kMT]) {
#pragma unroll
  for (int r = 0; r < kMT; ++r) {
#pragma unroll
    for (int c = 0; c < 4; ++c) {
      acc[c][r] = fmaf(w[c].x, av[r].x, acc[c][r]);
      acc[c][r] = fmaf(w[c].y, av[r].y, acc[c][r]);
      acc[c][r] = fmaf(w[c].z, av[r].z, acc[c][r]);
      acc[c][r] = fmaf(w[c].w, av[r].w, acc[c][r]);
    }
  }
}

// Four STRIDED columns {j, j+P, j+2P, j+3P} x kMT rows.
// Weights: U0/U1 = k-rows (k4,k4+1), V0/V1 = (k4+2,k4+3), persistent across
// phases (caller preloads k4 0..3 once; mv4 re-loads them at its END so the
// loads fly during combine+barrier and cannot be sunk past __syncthreads).
// Activations: pair double-buffer A/B; the next pair's 8 ds_read_b128 issue
// before the current pair's 256 cyc of FMAs -> lgkm wait covered.
template <int NK4, int NCOLS, int AST, int PST>
__device__ __forceinline__ void mv4(const float4* __restrict__ pw,
                                    const float* __restrict__ a,
                                    float* __restrict__ pc,
                                    const float* __restrict__ bias,
                                    int j,
                                    float4 (&U0)[4], float4 (&U1)[4],
                                    float4 (&V0)[4], float4 (&V1)[4]) {
  constexpr int P = NCOLS / 4;
  float acc[4][kMT];
#pragma unroll
  for (int c = 0; c < 4; ++c) {
    const float b = bias[c * P + j];
#pragma unroll
    for (int r = 0; r < kMT; ++r) acc[c][r] = b;
  }
  float4 A0[kMT], A1[kMT], B0[kMT], B1[kMT];
#pragma unroll
  for (int r = 0; r < kMT; ++r) {
    A0[r] = *(const float4*)(a + r * AST + 0);
    A1[r] = *(const float4*)(a + r * AST + 4);
  }
  const float* ak = a;
#pragma unroll 1
  for (int k4 = 0; k4 + 8 <= NK4; k4 += 4) {
    // acts pair B = (k4+2, k4+3): issue before the A FMAs
#pragma unroll
    for (int r = 0; r < kMT; ++r) {
      B0[r] = *(const float4*)(ak + r * AST + 8);
      B1[r] = *(const float4*)(ak + r * AST + 12);
    }
    fma4r(U0, A0, acc);
    fma4r(U1, A1, acc);
    // weight prefetch (k4+4, k4+5)
    wload4<NCOLS>(pw, U0, k4 + 4);
    wload4<NCOLS>(pw, U1, k4 + 5);
    // acts pair A' = (k4+4, k4+5): issue before the B FMAs
#pragma unroll
    for (int r = 0; r < kMT; ++r) {
      A0[r] = *(const float4*)(ak + r * AST + 16);
      A1[r] = *(const float4*)(ak + r * AST + 20);
    }
    fma4r(V0, B0, acc);
    fma4r(V1, B1, acc);
    // weight prefetch (k4+6, k4+7)
    wload4<NCOLS>(pw, V0, k4 + 6);
    wload4<NCOLS>(pw, V1, k4 + 7);
    ak += 16;
  }
  // tail (last 4 k4s): A pair + U/V weights resident; load B pair
#pragma unroll
  for (int r = 0; r < kMT; ++r) {
    B0[r] = *(const float4*)(ak + r * AST + 8);
    B1[r] = *(const float4*)(ak + r * AST + 12);
  }
  fma4r(U0, A0, acc);
  fma4r(U1, A1, acc);
  fma4r(V0, B0, acc);
  fma4r(V1, B1, acc);
  // store pre-acts (lane-contiguous ds_write_b32, conflict-free)
#pragma unroll
  for (int r = 0; r < kMT; ++r)
#pragma unroll
    for (int c = 0; c < 4; ++c) pc[r * PST + c * P + j] = acc[c][r];
  // reload k4 0..3 for the NEXT phase; lands during combine + barrier
  wload4<NCOLS>(pw, U0, 0);
  wload4<NCOLS>(pw, U1, 1);
  wload4<NCOLS>(pw, V0, 2);
  wload4<NCOLS>(pw, V1, 3);
}

__device__ __forceinline__ float cfc_combine(float p1, float p2, float pt) {
  float f1 = tanhf(p1);
  float f2 = tanhf(p2);
  float ti = 1.0f / (1.0f + expf(-pt));
  return f1 + ti * (f2 - f1);
}

// ---------------------------------------------------------------------------
// Pipelined persistent kernel. Phase p runs matvecs c0@t=p, c1@t=p-1,
// c2@t=p-2 plus the fc head for t=p-3, then combines (spread over 640
// threads as row-jobs) + x prefetch on [640,768).
// Matvec wave map: waves 0-3 c0, 4-6 c1, 7 c2, 11 fc head.
// ---------------------------------------------------------------------------
__global__ __launch_bounds__(kNT, 3) void ncp_main(
    const float* __restrict__ x, const float* __restrict__ hidden,
    const float* __restrict__ ws, const float* __restrict__ fcw,
    const float* __restrict__ fcb, float* __restrict__ out) {
  __shared__ __align__(16) float xc0[kMT][kS0];   // [x_t | h0 | pad]
  __shared__ __align__(16) float xc1[kMT][kS1];   // [n0  | h1]
  __shared__ __align__(16) float xc2[kMT][kS2];   // [n1  | h2 | pad]
  __shared__ __align__(16) float pa0[kMT][kC0p];  // pre-act cell0
  __shared__ __align__(16) float pa1[kMT][kC1p];  // pre-act cell1
  __shared__ __align__(16) float pa2[kMT][kC2p];  // pre-act cell2
  __shared__ float s_fcwT[64 * 64];               // fc_w transposed [m][o]
  __shared__ float s_bc[kBCN];
  __shared__ float s_fcb[64];

  const int tid = threadIdx.x;
  const int b0 = blockIdx.x * kMT;

  // zero xc (k-padding lanes must be 0.0f, not garbage: 0*NaN = NaN)
#pragma unroll
  for (int r = 0; r < kMT; ++r) {
    if (tid < kS0) xc0[r][tid] = 0.0f;
    if (tid < kS1) xc1[r][tid] = 0.0f;
    if (tid < kS2) xc2[r][tid] = 0.0f;
  }
  __syncthreads();
  // initial hidden state -> h slots
  for (int i = tid; i < kMT * kUNITS; i += kNT) {
    int r = i >> 9, u = i & 511;
    float v = hidden[(size_t)(b0 + r) * kUNITS + u];
    if (u < kINTER) xc0[r][kDIN + u] = v;
    else if (u < kINTER + kCMD) xc1[r][u] = v;  // layout offset == u
    else xc2[r][kCMD + (u - (kINTER + kCMD))] = v;
  }
  for (int i = tid; i < kBCN; i += kNT) s_bc[i] = ws[kBCOff + i];
  if (tid < 64) s_fcb[tid] = fcb[tid];
  for (int i = tid; i < 64 * 64; i += kNT) {
    int m = i >> 6, o = i & 63;
    s_fcwT[i] = fcw[o * 64 + m];
  }
  if (tid < 128) {  // stage x(0): 4 rows x 128 floats = 128 float4
    int r = tid >> 5, d4 = tid & 31;
    *(float4*)&xc0[r][d4 * 4] =
        *(const float4*)&x[(size_t)(b0 + r) * (kT * kDIN) + d4 * 4];
  }

  const float4* wp0 = (const float4*)ws;
  const float4* wp1 = wp0 + kQ0;
  const float4* wp2 = wp1 + kQ1;

  // persistent weight registers (k4 0..3 of this thread's column set)
  float4 U0[4], U1[4], V0[4], V1[4];
  if (tid < kP0) {
    const float4* pw = wp0 + tid;
    wload4<kC0p>(pw, U0, 0); wload4<kC0p>(pw, U1, 1);
    wload4<kC0p>(pw, V0, 2); wload4<kC0p>(pw, V1, 3);
  } else if (tid >= 256 && tid < 256 + kP1) {
    const float4* pw = wp1 + (tid - 256);
    wload4<kC1p>(pw, U0, 0); wload4<kC1p>(pw, U1, 1);
    wload4<kC1p>(pw, V0, 2); wload4<kC1p>(pw, V1, 3);
  } else if (tid >= 448 && tid < 448 + kP2) {
    const float4* pw = wp2 + (tid - 448);
    wload4<kC2p>(pw, U0, 0); wload4<kC2p>(pw, U1, 1);
    wload4<kC2p>(pw, V0, 2); wload4<kC2p>(pw, V1, 3);
  }
  __syncthreads();

  for (int p = 0; p < kT + 3; ++p) {
    // ================= matvec + fc section =================
    if (tid < 256) {
      if (p < kT && tid < kP0)
        mv4<kK40, kC0p, kS0, kC0p>(wp0 + tid, &xc0[0][0], &pa0[0][0], s_bc,
                                   tid, U0, U1, V0, V1);
    } else if (tid < 448) {
      const int pi = tid - 256;
      if (p >= 1 && p <= kT && pi < kP1)
        mv4<kK41, kC1p, kS1, kC1p>(wp1 + pi, &xc1[0][0], &pa1[0][0],
                                   s_bc + kC0p, pi, U0, U1, V0, V1);
    } else if (tid < 512) {
      const int pi = tid - 448;
      if (p >= 2 && p <= kT + 1 && pi < kP2)
        mv4<kK42, kC2p, kS2, kC2p>(wp2 + pi, &xc2[0][0], &pa2[0][0],
                                   s_bc + kC0p + kC1p, pi, U0, U1, V0, V1);
    } else if (tid >= 704) {
      // wave 11: fc head for t = p-3; reads n2(t) left in xc2 by comb2@p-1.
      if (p >= 3) {
        const int o = tid - 704;  // 0..63
        const int t_fc = p - 3;
        float a0 = s_fcb[o], a1 = a0, a2 = a0, a3 = a0;
        for (int m = 0; m < kMOTOR; ++m) {
          float w = s_fcwT[m * 64 + o];
          a0 = fmaf(xc2[0][kCMD + m], w, a0);
          a1 = fmaf(xc2[1][kCMD + m], w, a1);
          a2 = fmaf(xc2[2][kCMD + m], w, a2);
          a3 = fmaf(xc2[3][kCMD + m], w, a3);
        }
        size_t base =
            (size_t)b0 * (kT * kOUT) + (size_t)t_fc * kOUT + o;
        const size_t rstride = (size_t)kT * kOUT;
        out[base] = a0;
        out[base + rstride] = a1;
        out[base + 2 * rstride] = a2;
        out[base + 3 * rstride] = a3;
      }
    }
    __syncthreads();
    // ================= combine (row-jobs) + stage section =================
    if (tid < kCW) {
      for (int g = tid; g < kJ2; g += kCW) {
        if (g < kJ0) {
          if (p < kT) {
            const int col = g >> 2, r = g & 3;
            float v = cfc_combine(pa0[r][col], pa0[r][col + kINTER],
                                  pa0[r][col + 2 * kINTER]);
            xc1[r][col] = v;          // input to c1 (next phase)
            xc0[r][kDIN + col] = v;   // h0 for c0@p+1
          }
        } else if (g < kJ1) {
          if (p >= 1 && p <= kT) {
            const int gg = g - kJ0;
            const int col = gg >> 2, r = gg & 3;
            float v = cfc_combine(pa1[r][col], pa1[r][col + kCMD],
                                  pa1[r][col + 2 * kCMD]);
            xc2[r][col] = v;          // input to c2 (next phase)
            xc1[r][kINTER + col] = v; // h1
          }
        } else {
          if (p >= 2 && p <= kT + 1) {
            const int gg = g - kJ1;
            const int col = gg >> 2, r = gg & 3;
            float v = cfc_combine(pa2[r][col], pa2[r][col + kMOTOR],
                                  pa2[r][col + 2 * kMOTOR]);
            xc2[r][kCMD + col] = v;   // h2 == n2(t) -> fc head @p+1
          }
        }
      }
    } else {
      if (p + 1 < kT) {  // prefetch x(p+1) for next phase's c0
        const int i2 = tid - kCW;   // 0..127
        const int r = i2 >> 5, d4 = i2 & 31;
        *(float4*)&xc0[r][d4 * 4] =
            *(const float4*)&x[(size_t)(b0 + r) * (kT * kDIN) +
                               (size_t)(p + 1) * kDIN + d4 * 4];
      }
    }
    __syncthreads();
  }

  // final hidden state: h0(255)/h1(255)/h2(255) are in the h slots
  const size_t hnoff = (size_t)kBatch * kT * kOUT;
  for (int i = tid; i < kMT * kUNITS; i += kNT) {
    int r = i >> 9, u = i & 511;
    float v;
    if (u < kINTER) v = xc0[r][kDIN + u];
    else if (u < kINTER + kCMD) v = xc1[r][u];
    else v = xc2[r][kCMD + (u - (kINTER + kCMD))];
    out[hnoff + (size_t)(b0 + r) * kUNITS + u] = v;
  }
}

// ---------------------------------------------------------------------------
extern "C" void kernel_launch(void* const* d_in, const int* in_sizes, int n_in,
                              void* d_out, int out_size, void* d_ws, size_t ws_size,
                              hipStream_t stream) {
  (void)in_sizes; (void)n_in; (void)out_size; (void)ws_size;
  const float* x = (const float*)d_in[0];
  const float* hidden = (const float*)d_in[1];
  const void* m0 = d_in[2];
  const void* m1 = d_in[3];
  const void* m2 = d_in[4];
  const float* f1w0 = (const float*)d_in[5];
  const float* f1b0 = (const float*)d_in[6];
  const float* f2w0 = (const float*)d_in[7];
  const float* f2b0 = (const float*)d_in[8];
  const float* taw0 = (const float*)d_in[9];
  const float* tab0 = (const float*)d_in[10];
  const float* tbw0 = (const float*)d_in[11];
  const float* tbb0 = (const float*)d_in[12];
  const float* f1w1 = (const float*)d_in[13];
  const float* f1b1 = (const float*)d_in[14];
  const float* f2w1 = (const float*)d_in[15];
  const float* f2b1 = (const float*)d_in[16];
  const float* taw1 = (const float*)d_in[17];
  const float* tab1 = (const float*)d_in[18];
  const float* tbw1 = (const float*)d_in[19];
  const float* tbb1 = (const float*)d_in[20];
  const float* f1w2 = (const float*)d_in[21];
  const float* f1b2 = (const float*)d_in[22];
  const float* f2w2 = (const float*)d_in[23];
  const float* f2b2 = (const float*)d_in[24];
  const float* taw2 = (const float*)d_in[25];
  const float* tab2 = (const float*)d_in[26];
  const float* tbw2 = (const float*)d_in[27];
  const float* tbb2 = (const float*)d_in[28];
  const float* fcw = (const float*)d_in[29];
  const float* fcb = (const float*)d_in[30];
  float* ws = (float*)d_ws;
  float* out = (float*)d_out;

  const int prep_items = kQ + kBCN;  // 155108
  prep_kernel<<<(prep_items + 255) / 256, 256, 0, stream>>>(
      m0, m1, m2,
      f1w0, f2w0, taw0, tbw0,
      f1w1, f2w1, taw1, tbw1,
      f1w2, f2w2, taw2, tbw2,
      f1b0, f2b0, tab0, tbb0,
      f1b1, f2b1, tab1, tbb1,
      f1b2, f2b2, tab2, tbb2,
      ws);

  ncp_main<<<kBatch / kMT, kNT, 0, stream>>>(x, hidden, ws, fcw, fcb, out);
}

// Round 6
// 7771.132 us; speedup vs baseline: 2.9085x; 2.9085x over previous
//
#include <hip/hip_runtime.h>
#include <math.h>

// ---------------------------------------------------------------------------
// NCPDecoder: 3-cell CfC RNN, B=1024, T=256.
// Round 8->9: recover from the R8 spill disaster; remove the pre-act
// round-trip instead of adding register state.
// R8 (22.6 ms): persistent W regs + act dbuf + launch_bounds(768,3) wanted
// ~180 VGPRs, allocator stayed at 84 -> everything spilled to scratch
// (FETCH 4.8 GB, 28 GB hbm). Never pin occupancy while adding live state.
// R9 (back to R7 geometry, ~18us LDS / ~18us L2-stream floors at kMT=4):
// one thread owns ONE hidden unit and computes ff1/ff2/t dots itself
// (3 acc), combines in-register, carries v[4] across the barrier, writes
// xc directly. Deletes pa LDS buffers (-50 KB), pa ds_writes, combine-
// phase reads, and the serialized combine section. Wave map (640 thr):
// waves 0-4 c0 (269u), 5-7 c1 (179u), 8 c2 (64u), 9 fc head + x prefetch.
// Depth-2 named ping-pong only (W0/W1,a0/a1), statically indexed, nothing
// register-resident across phases. Per-column k-order and bias-init
// unchanged -> identical numerics.
// ---------------------------------------------------------------------------

namespace {
constexpr int kBatch = 1024;
constexpr int kT     = 256;
constexpr int kDIN   = 128;
constexpr int kUNITS = 512;
constexpr int kINTER = 269;
constexpr int kCMD   = 179;
constexpr int kMOTOR = 64;
constexpr int kOUT   = 64;

constexpr int kCAT0 = kDIN + kINTER;    // 397
constexpr int kCAT1 = kINTER + kCMD;    // 448
constexpr int kCAT2 = kCMD + kMOTOR;    // 243

// k4 depths (exact ceil(cat/4)) ; LDS activation strides
constexpr int kNK40 = 100;              // ceil(397/4)
constexpr int kNK41 = 112;              // 448/4
constexpr int kNK42 = 61;               // ceil(243/4)
constexpr int kS0 = 400;                // 4*kNK40
constexpr int kS1 = 448;
constexpr int kS2 = 256;                // 244 rounded up (pad zeroed)

// weight quads per cell, layout W[(k4*3 + c)*NH + u], c in {ff1,ff2,t}
constexpr int kQ0 = kNK40 * 3 * kINTER; // 80700
constexpr int kQ1 = kNK41 * 3 * kCMD;   // 60144
constexpr int kQ2 = kNK42 * 3 * kMOTOR; // 11712
constexpr int kQ  = kQ0 + kQ1 + kQ2;    // 152556
// biases: per cell [c][u], c in {ff1,ff2,ta+tb}
constexpr int kB0 = 3 * kINTER;         // 807
constexpr int kB1 = 3 * kCMD;           // 537
constexpr int kB2 = 3 * kMOTOR;         // 192
constexpr int kBCN = kB0 + kB1 + kB2;   // 1536
constexpr int kBCOff = kQ * 4;          // float offset of biases in ws

constexpr int kMT = 4;     // batch rows per WG
constexpr int kNT = 640;   // threads per WG (10 waves)
}  // namespace

// Mask element-width detection. mask0 row 0, columns 128..396 are the
// structurally all-true h-block (full = concat([m, ones(n_h,n_h)]) then .T).
__device__ __forceinline__ int detect_mask_mode(const void* m0) {
  const unsigned int* w = (const unsigned int*)m0;
  if (w[32] == 0x01010101u && w[33] == 0x01010101u &&
      w[34] == 0x01010101u && w[35] == 0x01010101u)
    return 0;  // uint8
  if (w[128] == 0x3F800000u && w[129] == 0x3F800000u && w[130] == 0x3F800000u)
    return 2;  // f32
  return 1;    // int32
}

__device__ __forceinline__ bool mask_at(const void* mk, int idx, int mode) {
  if (mode == 0) return ((const unsigned char*)mk)[idx] != 0;
  if (mode == 1) return ((const int*)mk)[idx] != 0;
  return ((const float*)mk)[idx] != 0.0f;
}

// ---------------------------------------------------------------------------
// Prep: packed masked/fused weights, layout W[cell][(k4*3+c)*NH + u] quads.
// k-padding entries are exact zeros. Biases: [cell][c*NH + u].
// ---------------------------------------------------------------------------
__global__ void prep_kernel(
    const void* __restrict__ m0_, const void* __restrict__ m1_,
    const void* __restrict__ m2_,
    const float* __restrict__ f1w0, const float* __restrict__ f2w0,
    const float* __restrict__ taw0, const float* __restrict__ tbw0,
    const float* __restrict__ f1w1, const float* __restrict__ f2w1,
    const float* __restrict__ taw1, const float* __restrict__ tbw1,
    const float* __restrict__ f1w2, const float* __restrict__ f2w2,
    const float* __restrict__ taw2, const float* __restrict__ tbw2,
    const float* __restrict__ f1b0, const float* __restrict__ f2b0,
    const float* __restrict__ tab0, const float* __restrict__ tbb0,
    const float* __restrict__ f1b1, const float* __restrict__ f2b1,
    const float* __restrict__ tab1, const float* __restrict__ tbb1,
    const float* __restrict__ f1b2, const float* __restrict__ f2b2,
    const float* __restrict__ tab2, const float* __restrict__ tbb2,
    float* __restrict__ ws) {
  int i = blockIdx.x * 256 + threadIdx.x;
  const int mode = detect_mask_mode(m0_);
  if (i < kQ) {
    int qi, nh, cat, baseq;
    const void* mk;
    const float *wf1, *wf2, *wta, *wtb;
    if (i < kQ0) {
      qi = i; nh = kINTER; cat = kCAT0; mk = m0_;
      wf1 = f1w0; wf2 = f2w0; wta = taw0; wtb = tbw0; baseq = 0;
    } else if (i < kQ0 + kQ1) {
      qi = i - kQ0; nh = kCMD; cat = kCAT1; mk = m1_;
      wf1 = f1w1; wf2 = f2w1; wta = taw1; wtb = tbw1; baseq = kQ0;
    } else {
      qi = i - kQ0 - kQ1; nh = kMOTOR; cat = kCAT2; mk = m2_;
      wf1 = f1w2; wf2 = f2w2; wta = taw2; wtb = tbw2; baseq = kQ0 + kQ1;
    }
    const int k4  = qi / (3 * nh);
    const int rem = qi % (3 * nh);
    const int c   = rem / nh;
    const int u   = rem % nh;
    float v[4];
#pragma unroll
    for (int kk = 0; kk < 4; ++kk) {
      const int k = k4 * 4 + kk;
      float r = 0.0f;
      if (k < cat) {
        if (c == 0) {
          r = mask_at(mk, u * cat + k, mode) ? wf1[u * cat + k] : 0.0f;
        } else if (c == 1) {
          r = mask_at(mk, u * cat + k, mode) ? wf2[u * cat + k] : 0.0f;
        } else {
          r = wta[u * cat + k] + wtb[u * cat + k];
        }
      }
      v[kk] = r;
    }
    ((float4*)ws)[baseq + qi] = make_float4(v[0], v[1], v[2], v[3]);
  } else if (i < kQ + kBCN) {
    int j = i - kQ;
    int nh;
    const float *bf1, *bf2, *bta, *btb;
    if (j < kB0) {
      nh = kINTER; bf1 = f1b0; bf2 = f2b0; bta = tab0; btb = tbb0;
    } else if (j < kB0 + kB1) {
      j -= kB0; nh = kCMD; bf1 = f1b1; bf2 = f2b1; bta = tab1; btb = tbb1;
    } else {
      j -= kB0 + kB1; nh = kMOTOR; bf1 = f1b2; bf2 = f2b2; bta = tab2;
      btb = tbb2;
    }
    const int c = j / nh, u = j % nh;
    float r;
    if (c == 0) r = bf1[u];
    else if (c == 1) r = bf2[u];
    else r = bta[u] + btb[u];
    ws[kBCOff + (i - kQ)] = r;
  }
}

// 48 FMAs per k4: 3 chunk-weights x 4 rows x 4 lanes of the quad.
__device__ __forceinline__ void fma3(const float4 (&w)[3],
                                     const float4 (&av)[kMT],
                                     float (&acc)[3][kMT]) {
#pragma unroll
  for (int r = 0; r < kMT; ++r) {
#pragma unroll
    for (int c = 0; c < 3; ++c) {
      acc[c][r] = fmaf(w[c].x, av[r].x, acc[c][r]);
      acc[c][r] = fmaf(w[c].y, av[r].y, acc[c][r]);
      acc[c][r] = fmaf(w[c].z, av[r].z, acc[c][r]);
      acc[c][r] = fmaf(w[c].w, av[r].w, acc[c][r]);
    }
  }
}

__device__ __forceinline__ float cfc_combine(float p1, float p2, float pt) {
  float f1 = tanhf(p1);
  float f2 = tanhf(p2);
  float ti = 1.0f / (1.0f + expf(-pt));
  return f1 + ti * (f2 - f1);
}

// One hidden unit u: three dots (ff1/ff2/t) over cat, kMT rows, combined
// in-register. Depth-2 named ping-pong (W0/W1, a0/a1), all static indices.
template <int NK4, int NH, int AST>
__device__ __forceinline__ void mv3(const float4* __restrict__ pw,  // wbase+u
                                    const float* __restrict__ a,
                                    const float* __restrict__ bias, // cell base
                                    int u, float (&v)[kMT]) {
  float acc[3][kMT];
#pragma unroll
  for (int c = 0; c < 3; ++c) {
    const float b = bias[c * NH + u];
#pragma unroll
    for (int r = 0; r < kMT; ++r) acc[c][r] = b;
  }
  float4 W0[3], W1[3], a0[kMT], a1[kMT];
#pragma unroll
  for (int c = 0; c < 3; ++c) {
    W0[c] = pw[(0 * 3 + c) * NH];
    W1[c] = pw[(1 * 3 + c) * NH];
  }
#pragma unroll
  for (int r = 0; r < kMT; ++r) {
    a0[r] = *(const float4*)(a + r * AST + 0);
    a1[r] = *(const float4*)(a + r * AST + 4);
  }
  int k4 = 0;
#pragma unroll 1
  for (; k4 + 3 < NK4; k4 += 2) {
    fma3(W0, a0, acc);
#pragma unroll
    for (int c = 0; c < 3; ++c) W0[c] = pw[((k4 + 2) * 3 + c) * NH];
#pragma unroll
    for (int r = 0; r < kMT; ++r)
      a0[r] = *(const float4*)(a + r * AST + (k4 + 2) * 4);
    fma3(W1, a1, acc);
#pragma unroll
    for (int c = 0; c < 3; ++c) W1[c] = pw[((k4 + 3) * 3 + c) * NH];
#pragma unroll
    for (int r = 0; r < kMT; ++r)
      a1[r] = *(const float4*)(a + r * AST + (k4 + 3) * 4);
  }
  if constexpr (NK4 % 2 == 0) {
    // remaining 2 k4s resident
    fma3(W0, a0, acc);
    fma3(W1, a1, acc);
  } else {
    // remaining 3: load the last one behind the first FMA block
    fma3(W0, a0, acc);
#pragma unroll
    for (int c = 0; c < 3; ++c) W0[c] = pw[((k4 + 2) * 3 + c) * NH];
#pragma unroll
    for (int r = 0; r < kMT; ++r)
      a0[r] = *(const float4*)(a + r * AST + (k4 + 2) * 4);
    fma3(W1, a1, acc);
    fma3(W0, a0, acc);
  }
#pragma unroll
  for (int r = 0; r < kMT; ++r)
    v[r] = cfc_combine(acc[0][r], acc[1][r], acc[2][r]);
}

// ---------------------------------------------------------------------------
// Pipelined persistent kernel. Phase p: matvec c0@t=p / c1@t=p-1 / c2@t=p-2
// (fused combine, result in regs) + fc head t=p-3 on wave 9; barrier;
// write-back of results to xc + x(p+1) prefetch; barrier.
// ---------------------------------------------------------------------------
__global__ __launch_bounds__(kNT) void ncp_main(
    const float* __restrict__ x, const float* __restrict__ hidden,
    const float* __restrict__ ws, const float* __restrict__ fcw,
    const float* __restrict__ fcb, float* __restrict__ out) {
  __shared__ __align__(16) float xc0[kMT][kS0];   // [x_t | h0 | pad0]
  __shared__ __align__(16) float xc1[kMT][kS1];   // [n0  | h1]
  __shared__ __align__(16) float xc2[kMT][kS2];   // [n1  | h2 | pad0]
  __shared__ float s_fcwT[64 * 64];               // fc_w transposed [m][o]
  __shared__ float s_bc[kBCN];
  __shared__ float s_fcb[64];

  const int tid = threadIdx.x;
  const int b0 = blockIdx.x * kMT;

  // zero xc (k-padding lanes must be 0.0f, not garbage: 0*NaN = NaN)
#pragma unroll
  for (int r = 0; r < kMT; ++r) {
    if (tid < kS0) xc0[r][tid] = 0.0f;
    if (tid < kS1) xc1[r][tid] = 0.0f;
    if (tid < kS2) xc2[r][tid] = 0.0f;
  }
  __syncthreads();
  // initial hidden state -> h slots
  for (int i = tid; i < kMT * kUNITS; i += kNT) {
    int r = i >> 9, u = i & 511;
    float v = hidden[(size_t)(b0 + r) * kUNITS + u];
    if (u < kINTER) xc0[r][kDIN + u] = v;
    else if (u < kINTER + kCMD) xc1[r][u] = v;  // layout offset == u
    else xc2[r][kCMD + (u - (kINTER + kCMD))] = v;
  }
  for (int i = tid; i < kBCN; i += kNT) s_bc[i] = ws[kBCOff + i];
  if (tid < 64) s_fcb[tid] = fcb[tid];
  for (int i = tid; i < 64 * 64; i += kNT) {
    int m = i >> 6, o = i & 63;
    s_fcwT[i] = fcw[o * 64 + m];
  }
  if (tid < 128) {  // stage x(0): 4 rows x 128 floats = 128 float4
    int r = tid >> 5, d4 = tid & 31;
    *(float4*)&xc0[r][d4 * 4] =
        *(const float4*)&x[(size_t)(b0 + r) * (kT * kDIN) + d4 * 4];
  }
  __syncthreads();

  const float4* wp0 = (const float4*)ws;
  const float4* wp1 = wp0 + kQ0;
  const float4* wp2 = wp1 + kQ1;

  for (int p = 0; p < kT + 3; ++p) {
    float v[kMT];
    // ================= matvec (+fused combine) + fc section ==============
    if (tid < 320) {
      if (p < kT && tid < kINTER)
        mv3<kNK40, kINTER, kS0>(wp0 + tid, &xc0[0][0], s_bc, tid, v);
    } else if (tid < 512) {
      const int u = tid - 320;
      if (p >= 1 && p <= kT && u < kCMD)
        mv3<kNK41, kCMD, kS1>(wp1 + u, &xc1[0][0], s_bc + kB0, u, v);
    } else if (tid < 576) {
      const int u = tid - 512;
      if (p >= 2 && p <= kT + 1)
        mv3<kNK42, kMOTOR, kS2>(wp2 + u, &xc2[0][0], s_bc + kB0 + kB1, u, v);
    } else {
      // wave 9: fc head for t = p-3; reads n2(t) written at phase p-1.
      if (p >= 3) {
        const int o = tid - 576;  // 0..63
        const int t_fc = p - 3;
        float a0 = s_fcb[o], a1 = a0, a2 = a0, a3 = a0;
        for (int m = 0; m < kMOTOR; ++m) {
          float w = s_fcwT[m * 64 + o];
          a0 = fmaf(xc2[0][kCMD + m], w, a0);
          a1 = fmaf(xc2[1][kCMD + m], w, a1);
          a2 = fmaf(xc2[2][kCMD + m], w, a2);
          a3 = fmaf(xc2[3][kCMD + m], w, a3);
        }
        size_t base = (size_t)b0 * (kT * kOUT) + (size_t)t_fc * kOUT + o;
        const size_t rstride = (size_t)kT * kOUT;
        out[base] = a0;
        out[base + rstride] = a1;
        out[base + 2 * rstride] = a2;
        out[base + 3 * rstride] = a3;
      }
    }
    __syncthreads();
    // ================= write-back + x prefetch section ===================
    if (tid < 320) {
      if (p < kT && tid < kINTER) {
#pragma unroll
        for (int r = 0; r < kMT; ++r) {
          xc1[r][tid] = v[r];          // input to c1 (next phase)
          xc0[r][kDIN + tid] = v[r];   // h0 for c0@p+1
        }
      }
    } else if (tid < 512) {
      const int u = tid - 320;
      if (p >= 1 && p <= kT && u < kCMD) {
#pragma unroll
        for (int r = 0; r < kMT; ++r) {
          xc2[r][u] = v[r];            // input to c2 (next phase)
          xc1[r][kINTER + u] = v[r];   // h1
        }
      }
    } else if (tid < 576) {
      const int u = tid - 512;
      if (p >= 2 && p <= kT + 1) {
#pragma unroll
        for (int r = 0; r < kMT; ++r)
          xc2[r][kCMD + u] = v[r];     // h2 == n2(t) -> fc head @p+1
      }
    } else {
      if (p + 1 < kT) {  // prefetch x(p+1): 128 quads on 64 threads
        const int i2 = tid - 576;  // 0..63
#pragma unroll
        for (int q = 0; q < 2; ++q) {
          const int idx = i2 + q * 64;
          const int r = idx >> 5, d4 = idx & 31;
          *(float4*)&xc0[r][d4 * 4] =
              *(const float4*)&x[(size_t)(b0 + r) * (kT * kDIN) +
                                 (size_t)(p + 1) * kDIN + d4 * 4];
        }
      }
    }
    __syncthreads();
  }

  // final hidden state: h0(255)/h1(255)/h2(255) are in the h slots
  const size_t hnoff = (size_t)kBatch * kT * kOUT;
  for (int i = tid; i < kMT * kUNITS; i += kNT) {
    int r = i >> 9, u = i & 511;
    float v;
    if (u < kINTER) v = xc0[r][kDIN + u];
    else if (u < kINTER + kCMD) v = xc1[r][u];
    else v = xc2[r][kCMD + (u - (kINTER + kCMD))];
    out[hnoff + (size_t)(b0 + r) * kUNITS + u] = v;
  }
}

// ---------------------------------------------------------------------------
extern "C" void kernel_launch(void* const* d_in, const int* in_sizes, int n_in,
                              void* d_out, int out_size, void* d_ws, size_t ws_size,
                              hipStream_t stream) {
  (void)in_sizes; (void)n_in; (void)out_size; (void)ws_size;
  const float* x = (const float*)d_in[0];
  const float* hidden = (const float*)d_in[1];
  const void* m0 = d_in[2];
  const void* m1 = d_in[3];
  const void* m2 = d_in[4];
  const float* f1w0 = (const float*)d_in[5];
  const float* f1b0 = (const float*)d_in[6];
  const float* f2w0 = (const float*)d_in[7];
  const float* f2b0 = (const float*)d_in[8];
  const float* taw0 = (const float*)d_in[9];
  const float* tab0 = (const float*)d_in[10];
  const float* tbw0 = (const float*)d_in[11];
  const float* tbb0 = (const float*)d_in[12];
  const float* f1w1 = (const float*)d_in[13];
  const float* f1b1 = (const float*)d_in[14];
  const float* f2w1 = (const float*)d_in[15];
  const float* f2b1 = (const float*)d_in[16];
  const float* taw1 = (const float*)d_in[17];
  const float* tab1 = (const float*)d_in[18];
  const float* tbw1 = (const float*)d_in[19];
  const float* tbb1 = (const float*)d_in[20];
  const float* f1w2 = (const float*)d_in[21];
  const float* f1b2 = (const float*)d_in[22];
  const float* f2w2 = (const float*)d_in[23];
  const float* f2b2 = (const float*)d_in[24];
  const float* taw2 = (const float*)d_in[25];
  const float* tab2 = (const float*)d_in[26];
  const float* tbw2 = (const float*)d_in[27];
  const float* tbb2 = (const float*)d_in[28];
  const float* fcw = (const float*)d_in[29];
  const float* fcb = (const float*)d_in[30];
  float* ws = (float*)d_ws;
  float* out = (float*)d_out;

  const int prep_items = kQ + kBCN;  // 154092
  prep_kernel<<<(prep_items + 255) / 256, 256, 0, stream>>>(
      m0, m1, m2,
      f1w0, f2w0, taw0, tbw0,
      f1w1, f2w1, taw1, tbw1,
      f1w2, f2w2, taw2, tbw2,
      f1b0, f2b0, tab0, tbb0,
      f1b1, f2b1, tab1, tbb1,
      f1b2, f2b2, tab2, tbb2,
      ws);

  ncp_main<<<kBatch / kMT, kNT, 0, stream>>>(x, hidden, ws, fcw, fcb, out);
}